// Round 5
// baseline (303.085 us; speedup 1.0000x reference)
//
#include <hip/hip_runtime.h>
#include <hip/hip_bf16.h>
#include <cstdint>

typedef __attribute__((ext_vector_type(4))) float f32x4;
typedef __attribute__((ext_vector_type(16))) float f32x16;
typedef __attribute__((ext_vector_type(8))) short bf16x8;
typedef __attribute__((ext_vector_type(4))) unsigned int u32x4;
typedef unsigned short u16;
typedef unsigned int u32;

__device__ __forceinline__ u16 f2b(float x) {
  __hip_bfloat16 h = __float2bfloat16(x);
  return *reinterpret_cast<u16*>(&h);
}

__device__ __forceinline__ u32 pk(float a, float b) {
  return ((u32)f2b(b) << 16) | (u32)f2b(a);
}

__device__ __forceinline__ void gload16(const void* g, void* l) {
  __builtin_amdgcn_global_load_lds((const __attribute__((address_space(1))) u32*)g,
                                   (__attribute__((address_space(3))) u32*)l, 16, 0, 0);
}

__device__ __forceinline__ float xmax32(float x) {
  return fmaxf(x, __shfl_xor(x, 32, 64));
}
__device__ __forceinline__ float xsum32(float x) {
  return x + __shfl_xor(x, 32, 64);
}

// ---------------- converts ----------------

__global__ void cvt_f32_bf16(const float* __restrict__ in, u16* __restrict__ out, int n4) {
  int idx = (blockIdx.x * 256 + threadIdx.x);
  if (idx < n4) {
    const float4 v = *(const float4*)(in + (size_t)idx * 4);
    u16* o = out + (size_t)idx * 4;
    o[0] = f2b(v.x); o[1] = f2b(v.y); o[2] = f2b(v.z); o[3] = f2b(v.w);
  }
}

__global__ void w_transpose_cvt(const float* __restrict__ w0, const float* __restrict__ w1,
                                const float* __restrict__ w2, int b0, int b1,
                                int N0, int N1, int N2,
                                u16* __restrict__ out, int K) {
  __shared__ float tile[32][33];
  int k0 = blockIdx.x * 32, n0 = blockIdx.y * 32;
  const float* src; int srcN; int c0;
  if (n0 < b0)      { src = w0; srcN = N0; c0 = n0; }
  else if (n0 < b1) { src = w1; srcN = N1; c0 = n0 - b0; }
  else              { src = w2; srcN = N2; c0 = n0 - b1; }
  int tx = threadIdx.x & 31, ty = threadIdx.x >> 5;
#pragma unroll
  for (int j = 0; j < 32; j += 8)
    tile[ty + j][tx] = src[(size_t)(k0 + ty + j) * srcN + c0 + tx];
  __syncthreads();
#pragma unroll
  for (int j = 0; j < 32; j += 8)
    out[(size_t)(n0 + ty + j) * K + k0 + tx] = f2b(tile[tx][ty + j]);
}

__global__ void pack_bias(const float* __restrict__ bq, const float* __restrict__ bk,
                          const float* __restrict__ bv, float* __restrict__ out) {
  int i = blockIdx.x * 256 + threadIdx.x;
  if (i < 3072) out[i] = (i < 2048) ? bq[i] : ((i < 2560) ? bk[i - 2048] : bv[i - 2560]);
}

__global__ void v_transpose_cvt(const float* __restrict__ qkv, u16* __restrict__ vt) {
  __shared__ float tile[32][33];
  int s0 = blockIdx.x * 32;
  int d0 = blockIdx.y * 32;
  int z = blockIdx.z;              // b*4 + kvh
  int b = z >> 2, kvh = z & 3;
  int tx = threadIdx.x & 31, ty = threadIdx.x >> 5;
#pragma unroll
  for (int j = 0; j < 32; j += 8)
    tile[ty + j][tx] = qkv[((size_t)(b * 2048 + s0 + ty + j)) * 3072 + 2560 + kvh * 128 + d0 + tx];
  __syncthreads();
#pragma unroll
  for (int j = 0; j < 32; j += 8)
    vt[((size_t)z * 128 + d0 + ty + j) * 2048 + s0 + tx] = f2b(tile[tx][ty + j]);
}

// ---------------- RoPE ----------------
__global__ void rope_cvt(const float* __restrict__ qkv, u16* __restrict__ out,
                         int lognh, int col0, float scale) {
  int idx = blockIdx.x * 256 + threadIdx.x;   // pair index
  int i = idx & 63;                            // pair within head
  int nh = 1 << lognh;
  int h = (idx >> 6) & (nh - 1);
  int bs = idx >> (6 + lognh);                 // 0..4095
  int s = bs & 2047;
  int b = bs >> 11;
  const float* src = qkv + (size_t)bs * 3072 + col0 + h * 128 + 2 * i;
  float tr = src[0], ti = src[1];
  float theta = expf(-(float)i * 0.14391156831212787f);  // ln(10000)/64
  float ang = (float)s * theta;
  float sv, cv;
  sincosf(ang, &sv, &cv);
  float orr = (tr * cv - ti * sv) * scale;
  float oii = (tr * sv + ti * cv) * scale;
  u16* dst = out + (((size_t)(b * nh + h) * 2048 + s) * 128 + 2 * i);
  dst[0] = f2b(orr);
  dst[1] = f2b(oii);
}

// ---------------- GEMM (m97 structure): C = A @ Bt^T + bias ----------------
__global__ __launch_bounds__(256) void gemm_bt_bf16(
    const u16* __restrict__ A, const u16* __restrict__ Bt,
    const float* __restrict__ bias, float* __restrict__ C,
    int M, int N, int K) {
  __shared__ u16 As[128 * 32];
  __shared__ u16 Bs[128 * 32];
  const int tid = threadIdx.x;
  const int lane = tid & 63;
  const int w = tid >> 6;
  const int wr = w >> 1, wc = w & 1;
  const int m0 = blockIdx.y * 128;
  const int n0 = blockIdx.x * 128;

  f32x4 acc[4][4] = {};

  for (int k0 = 0; k0 < K; k0 += 32) {
#pragma unroll
    for (int it = 0; it < 2; ++it) {
      int c = tid + it * 256;
      int row = c >> 2;
      int off = (c & 3) * 8;
      gload16(A + (size_t)(m0 + row) * K + k0 + off, (u16*)As + w * 512 + it * 2048);
      gload16(Bt + (size_t)(n0 + row) * K + k0 + off, (u16*)Bs + w * 512 + it * 2048);
    }
    __syncthreads();
    const int col8 = (lane >> 4) * 8;
    bf16x8 a[4], bfr[4];
#pragma unroll
    for (int m = 0; m < 4; ++m)
      a[m] = *(const bf16x8*)&As[(wr * 64 + m * 16 + (lane & 15)) * 32 + col8];
#pragma unroll
    for (int n = 0; n < 4; ++n)
      bfr[n] = *(const bf16x8*)&Bs[(wc * 64 + n * 16 + (lane & 15)) * 32 + col8];
#pragma unroll
    for (int m = 0; m < 4; ++m)
#pragma unroll
      for (int n = 0; n < 4; ++n)
        acc[m][n] = __builtin_amdgcn_mfma_f32_16x16x32_bf16(a[m], bfr[n], acc[m][n], 0, 0, 0);
    __syncthreads();
  }

#pragma unroll
  for (int m = 0; m < 4; ++m) {
    int row = m0 + wr * 64 + m * 16 + ((lane >> 4) << 2);
#pragma unroll
    for (int n = 0; n < 4; ++n) {
      int col = n0 + wc * 64 + n * 16 + (lane & 15);
      float bvv = bias ? bias[col] : 0.f;
      float* cp = C + (size_t)row * N + col;
#pragma unroll
      for (int r = 0; r < 4; ++r) cp[(size_t)r * N] = acc[m][n][r] + bvv;
    }
  }
}

// ---------------- flash attention v5 ----------------
// Qr: (B*H, 2048, 128) bf16 pre-scaled by 1/sqrt(128).
// Kr: (B*KVH, 2048, 128) bf16.  Vt: (B*KVH, 128, 2048) bf16.
// Att out: (B*2048, 2048) bf16.
// 2 waves x 64 q-rows = 128 q/block; KVBLK=32, double-buffered 32KB LDS;
// each wave runs TWO 32-row q-sub-blocks sharing kf/vb LDS fragments
// (halves LDS read per unit work — LDS pipe was the wall).
__global__ __launch_bounds__(128, 1) void flash_attn(
    const u16* __restrict__ Qr, const u16* __restrict__ Kr,
    const u16* __restrict__ Vt, u16* __restrict__ Att) {
  __shared__ u16 Ks[2][32 * 128];   // 8KB/buf: 32 rows x 256B, slot ^= row&7
  __shared__ u16 Vs[2][128 * 32];   // 8KB/buf: 128 rows x 64B, slot ^= (row>>1)&3
  const int tid = threadIdx.x, lane = tid & 63, w = tid >> 6;
  const int lo = lane & 31, hi = lane >> 5;
  const int q0 = blockIdx.x * 128 + w * 64;
  const int h = blockIdx.y, b = blockIdx.z;
  const int kvh = h >> 2;

  const char* Khead = (const char*)(Kr + (size_t)(b * 4 + kvh) * 2048 * 128);
  const char* Vhead = (const char*)(Vt + (size_t)(b * 4 + kvh) * 128 * 2048);

  // Q fragments for both q-sub-blocks (B-operand of swapped QK^T)
  bf16x8 qf0[8], qf1[8];
  {
    const u16* qp = Qr + ((size_t)(b * 16 + h) * 2048 + q0 + lo) * 128 + hi * 8;
#pragma unroll
    for (int ds = 0; ds < 8; ++ds) qf0[ds] = *(const bf16x8*)(qp + ds * 16);
    qp += (size_t)32 * 128;
#pragma unroll
    for (int ds = 0; ds < 8; ++ds) qf1[ds] = *(const bf16x8*)(qp + ds * 16);
  }

#define STAGE(bufi, t)                                                        \
  {                                                                           \
    _Pragma("unroll")                                                         \
    for (int it = 0; it < 4; ++it) {                                          \
      int c = it * 128 + tid;                                                 \
      int krow = c >> 4;                                                      \
      int koff = krow * 256 + ((c & 15) << 4 ^ ((krow & 7) << 4));            \
      gload16(Khead + (size_t)(t) * 8192 + koff,                              \
              (u16*)Ks[bufi] + it * 1024 + w * 512);                          \
      int vrow = c >> 2;                                                      \
      int voff = vrow * 4096 + ((c & 3) << 4 ^ (((vrow >> 1) & 3) << 4));     \
      gload16(Vhead + (size_t)(t) * 64 + voff,                                \
              (u16*)Vs[bufi] + it * 1024 + w * 512);                          \
    }                                                                         \
  }

  f32x16 o0[4] = {}, o1[4] = {};
  float m_run0 = -3.0e38f, l_run0 = 0.f;
  float m_run1 = -3.0e38f, l_run1 = 0.f;
  const int swz = (lo & 7) << 4;
  const int vswz = ((lo >> 1) & 3) << 4;
  const int hi16 = hi * 16;

  STAGE(0, 0);
  __syncthreads();

  int buf = 0;
  for (int t = 0; t < 64; ++t) {
    int tn = (t < 63) ? t + 1 : 63;
    STAGE(buf ^ 1, tn);

    const char* Kb = (const char*)Ks[buf];
    const char* Vb = (const char*)Vs[buf];

    // QK^T (swapped): both q-subs share each kf fragment
    f32x16 s0 = {}, s1 = {};
    __builtin_amdgcn_s_setprio(1);
#pragma unroll
    for (int ds = 0; ds < 8; ++ds) {
      bf16x8 kf = *(const bf16x8*)(Kb + lo * 256 + ((ds * 32 + hi16) ^ swz));
      s0 = __builtin_amdgcn_mfma_f32_32x32x16_bf16(kf, qf0[ds], s0, 0, 0, 0);
      s1 = __builtin_amdgcn_mfma_f32_32x32x16_bf16(kf, qf1[ds], s1, 0, 0, 0);
    }
    __builtin_amdgcn_s_setprio(0);

    // online softmax + P-repack per q-sub (round-4-verified math)
    bf16x8 paA0, paB0, paA1, paB1;
#define SOFTPASS(S, MR, LR, OA, PA, PB)                                       \
    {                                                                         \
      float m01 = fmaxf(fmaxf(S[0], S[1]), fmaxf(S[2], S[3]));                \
      float m23 = fmaxf(fmaxf(S[4], S[5]), fmaxf(S[6], S[7]));                \
      float m45 = fmaxf(fmaxf(S[8], S[9]), fmaxf(S[10], S[11]));              \
      float m67 = fmaxf(fmaxf(S[12], S[13]), fmaxf(S[14], S[15]));            \
      float pmax = xmax32(fmaxf(fmaxf(m01, m23), fmaxf(m45, m67)));           \
      if (!__all(pmax - MR <= 8.0f)) {                                        \
        float mnew = fmaxf(MR, pmax);                                         \
        float rs = __expf(MR - mnew);                                         \
        MR = mnew;                                                            \
        LR *= rs;                                                             \
        _Pragma("unroll")                                                     \
        for (int r = 0; r < 16; ++r) {                                        \
          float rsr = __shfl(rs, (r & 3) + 8 * (r >> 2) + 4 * hi, 64);        \
          OA[0][r] *= rsr; OA[1][r] *= rsr; OA[2][r] *= rsr; OA[3][r] *= rsr; \
        }                                                                     \
      }                                                                       \
      float lsum = 0.f;                                                       \
      _Pragma("unroll")                                                       \
      for (int r = 0; r < 16; ++r) {                                          \
        float p = __expf(S[r] - MR); S[r] = p; lsum += p;                     \
      }                                                                       \
      LR += xsum32(lsum);                                                     \
      u32 a0 = pk(S[0], S[1]),   a1 = pk(S[2], S[3]);                         \
      u32 b0 = pk(S[4], S[5]),   b1 = pk(S[6], S[7]);                         \
      u32 t0 = hi ? a0 : b0, t1 = hi ? a1 : b1;                               \
      u32 r0 = __shfl_xor(t0, 32, 64), r1 = __shfl_xor(t1, 32, 64);           \
      u32x4 w0;                                                               \
      w0[0] = hi ? r0 : a0; w0[1] = hi ? r1 : a1;                             \
      w0[2] = hi ? b0 : r0; w0[3] = hi ? b1 : r1;                             \
      PA = __builtin_bit_cast(bf16x8, w0);                                    \
      u32 c0 = pk(S[8], S[9]),   c1 = pk(S[10], S[11]);                       \
      u32 d0 = pk(S[12], S[13]), d1 = pk(S[14], S[15]);                       \
      u32 t2 = hi ? c0 : d0, t3 = hi ? c1 : d1;                               \
      u32 r2 = __shfl_xor(t2, 32, 64), r3 = __shfl_xor(t3, 32, 64);           \
      u32x4 w1;                                                               \
      w1[0] = hi ? r2 : c0; w1[1] = hi ? r3 : c1;                             \
      w1[2] = hi ? d0 : r2; w1[3] = hi ? d1 : r3;                             \
      PB = __builtin_bit_cast(bf16x8, w1);                                    \
    }
    SOFTPASS(s0, m_run0, l_run0, o0, paA0, paB0)
    SOFTPASS(s1, m_run1, l_run1, o1, paA1, paB1)

    // PV: vb fragments shared by both q-subs
    __builtin_amdgcn_s_setprio(1);
#pragma unroll
    for (int n = 0; n < 4; ++n) {
      const char* vrb = Vb + (n * 32 + lo) * 64;
      bf16x8 vb0 = *(const bf16x8*)(vrb + ((0  + hi16) ^ vswz));
      bf16x8 vb1 = *(const bf16x8*)(vrb + ((32 + hi16) ^ vswz));
      o0[n] = __builtin_amdgcn_mfma_f32_32x32x16_bf16(paA0, vb0, o0[n], 0, 0, 0);
      o0[n] = __builtin_amdgcn_mfma_f32_32x32x16_bf16(paB0, vb1, o0[n], 0, 0, 0);
      o1[n] = __builtin_amdgcn_mfma_f32_32x32x16_bf16(paA1, vb0, o1[n], 0, 0, 0);
      o1[n] = __builtin_amdgcn_mfma_f32_32x32x16_bf16(paB1, vb1, o1[n], 0, 0, 0);
    }
    __builtin_amdgcn_s_setprio(0);

    __syncthreads();
    buf ^= 1;
  }

  // epilogue: per q-sub, out rows = crow(r,hi), cols = n*32 + lo
  float inv0 = 1.0f / l_run0;
  float inv1 = 1.0f / l_run1;
  size_t rowbase = (size_t)(b * 2048 + q0);
#pragma unroll
  for (int r = 0; r < 16; ++r) {
    int rr = (r & 3) + 8 * (r >> 2) + 4 * hi;
    float iv0 = __shfl(inv0, rr, 64);
    float iv1 = __shfl(inv1, rr, 64);
    u16* op0 = Att + (rowbase + rr) * 2048 + h * 128 + lo;
    u16* op1 = Att + (rowbase + 32 + rr) * 2048 + h * 128 + lo;
    op0[0]  = f2b(o0[0][r] * iv0);
    op0[32] = f2b(o0[1][r] * iv0);
    op0[64] = f2b(o0[2][r] * iv0);
    op0[96] = f2b(o0[3][r] * iv0);
    op1[0]  = f2b(o1[0][r] * iv1);
    op1[32] = f2b(o1[1][r] * iv1);
    op1[64] = f2b(o1[2][r] * iv1);
    op1[96] = f2b(o1[3][r] * iv1);
  }
}

// ---------------- launch ----------------

extern "C" void kernel_launch(void* const* d_in, const int* in_sizes, int n_in,
                              void* d_out, int out_size, void* d_ws, size_t ws_size,
                              hipStream_t stream) {
  const float* x  = (const float*)d_in[0];
  const float* wq = (const float*)d_in[1];
  const float* bq = (const float*)d_in[2];
  const float* wk = (const float*)d_in[3];
  const float* bk = (const float*)d_in[4];
  const float* wv = (const float*)d_in[5];
  const float* bv = (const float*)d_in[6];
  const float* wo = (const float*)d_in[7];
  float* out = (float*)d_out;
  char* ws = (char*)d_ws;

  // workspace layout (bytes); att aliases x_bf (dead after QKV GEMM)
  u16*   x_bf   = (u16*)  (ws + 0);            // 16,777,216
  u16*   att    = (u16*)  (ws + 0);            // reuse after gemm1
  u16*   wqkv_t = (u16*)  (ws + 16777216);     // 12,582,912
  u16*   wo_t   = (u16*)  (ws + 29360128);     //  8,388,608
  float* biasq  = (float*)(ws + 37748736);     //     12,288
  float* qkv    = (float*)(ws + 37761024);     // 50,331,648
  u16*   q_r    = (u16*)  (ws + 88092672);     // 16,777,216
  u16*   k_r    = (u16*)  (ws + 104869888);    //  4,194,304
  u16*   v_t    = (u16*)  (ws + 109064192);    //  4,194,304  (end 113,258,496)

  // 1. converts
  cvt_f32_bf16<<<8192, 256, 0, stream>>>(x, x_bf, 2097152);
  w_transpose_cvt<<<dim3(64, 96), 256, 0, stream>>>(wq, wk, wv, 2048, 2560,
                                                    2048, 512, 512, wqkv_t, 2048);
  w_transpose_cvt<<<dim3(64, 64), 256, 0, stream>>>(wo, wo, wo, 2048, 2560,
                                                    2048, 2048, 2048, wo_t, 2048);
  pack_bias<<<12, 256, 0, stream>>>(bq, bk, bv, biasq);

  // 2. QKV projection: (4096 x 2048) @ (2048 x 3072) + bias -> fp32
  gemm_bt_bf16<<<dim3(24, 32), 256, 0, stream>>>(x_bf, wqkv_t, biasq, qkv, 4096, 3072, 2048);

  // 3. RoPE + layout (scale folded into Q); V transpose
  rope_cvt<<<16384, 256, 0, stream>>>(qkv, q_r, 4, 0, 0.08838834764831845f);
  rope_cvt<<<4096, 256, 0, stream>>>(qkv, k_r, 2, 2048, 1.0f);
  v_transpose_cvt<<<dim3(64, 4, 8), 256, 0, stream>>>(qkv, v_t);

  // 4. flash attention -> att bf16
  flash_attn<<<dim3(16, 16, 2), 128, 0, stream>>>(q_r, k_r, v_t, att);

  // 5. out projection: (4096 x 2048) @ (2048 x 2048) -> d_out fp32
  gemm_bt_bf16<<<dim3(16, 32), 256, 0, stream>>>(att, wo_t, nullptr, out, 4096, 2048, 2048);
}